// Round 15
// baseline (204.851 us; speedup 1.0000x reference)
//
#include <hip/hip_runtime.h>

#define NN 20000
#define NE 320000
#define FD 128
#define KTOT 640   // logical K: 4*128 (relations) + 128 (root/self)
#define GK 512     // columns stored in g (root staged from source directly)
#define NSTEP 20   // KTOT / 32

typedef float f32x4 __attribute__((ext_vector_type(4)));
typedef __bf16 bf16x4 __attribute__((ext_vector_type(4)));
typedef __bf16 bf16x8 __attribute__((ext_vector_type(8)));

__device__ __forceinline__ unsigned f2ord(float f) {
  unsigned u = __float_as_uint(f);
  return (u & 0x80000000u) ? ~u : (u | 0x80000000u);
}
__device__ __forceinline__ float ord2f(unsigned u) {
  return (u & 0x80000000u) ? __uint_as_float(u & 0x7FFFFFFFu) : __uint_as_float(~u);
}
__device__ __forceinline__ unsigned pkbf(float a, float b) {
  union { __bf16 h[2]; unsigned u; } p;
  p.h[0] = (__bf16)a; p.h[1] = (__bf16)b; return p.u;
}
// async global->LDS, 16B per lane; LDS dest is wave-uniform base (lane*16 implied)
__device__ __forceinline__ void gld16(const void* src, void* lds) {
  __builtin_amdgcn_global_load_lds(
      (const unsigned int __attribute__((address_space(1)))*)src,
      (unsigned int __attribute__((address_space(3)))*)lds, 16, 0, 0);
}

// merged prep + histogram + minmax. Preconditions (single memset): deg=0,
// mm[0]=0 (complement-min seed), mm[1]=0 (max seed).
// mm[0] accumulates max(~ord) == ~min(ord); mm[1] accumulates max(ord).
__global__ void prep_hist_kernel(unsigned* mm, int* deg,
                                 const float* __restrict__ x, unsigned* __restrict__ xb,
                                 const float* __restrict__ W1, const float* __restrict__ r1,
                                 const float* __restrict__ W2, const float* __restrict__ r2,
                                 __bf16* __restrict__ wt1, __bf16* __restrict__ wt2,
                                 const int* __restrict__ dst, const float* __restrict__ ew) {
  __shared__ unsigned scm[256], smx[256];
  int i = blockIdx.x * blockDim.x + threadIdx.x;
  if (i < 2 * FD * KTOT) {
    int which = i / (FD * KTOT);
    int rem = i % (FD * KTOT);
    int n = rem / KTOT, k = rem % KTOT;
    const float* W = which ? W2 : W1;
    const float* rt = which ? r2 : r1;
    float v = (k < 512) ? W[(size_t)k * FD + n] : rt[(size_t)(k - 512) * FD + n];
    (which ? wt2 : wt1)[rem] = (__bf16)v;
  }
  if (i < NN * FD / 4) {
    float4 v = *(const float4*)(x + (size_t)i * 4);
    uint2 p;
    p.x = pkbf(v.x, v.y);
    p.y = pkbf(v.z, v.w);
    *(uint2*)(xb + (size_t)i * 2) = p;
  }
  // histogram + minmax (grid-stride; grid covers >= NE threads)
  unsigned lcm = 0u, lmx = 0u;  // complement-min, max
  for (int e = i; e < NE; e += gridDim.x * blockDim.x) {
    atomicAdd(&deg[dst[e]], 1);
    unsigned o = f2ord(ew[e]);
    unsigned c = ~o;
    lcm = (c > lcm) ? c : lcm;
    lmx = (o > lmx) ? o : lmx;
  }
  scm[threadIdx.x] = lcm; smx[threadIdx.x] = lmx;
  __syncthreads();
  for (int s = 128; s > 0; s >>= 1) {
    if (threadIdx.x < s) {
      unsigned a = scm[threadIdx.x], b = scm[threadIdx.x + s];
      scm[threadIdx.x] = (b > a) ? b : a;
      unsigned c = smx[threadIdx.x], d = smx[threadIdx.x + s];
      smx[threadIdx.x] = (d > c) ? d : c;
    }
    __syncthreads();
  }
  if (threadIdx.x == 0) { atomicMax(&mm[0], scm[0]); atomicMax(&mm[1], smx[0]); }
}

__global__ void scan_kernel(const int* __restrict__ deg, int* offs, int* cursor) {
  __shared__ int part[1024];
  const int CH = (NN + 1023) / 1024;  // 20
  int t = threadIdx.x;
  int b = t * CH;
  int e = (b + CH < NN) ? (b + CH) : NN;
  int s = 0;
  for (int i = b; i < e; ++i) s += deg[i];
  part[t] = s;
  __syncthreads();
  for (int off = 1; off < 1024; off <<= 1) {
    int v = part[t];
    int add = (t >= off) ? part[t - off] : 0;
    __syncthreads();
    part[t] = v + add;
    __syncthreads();
  }
  int excl = (t == 0) ? 0 : part[t - 1];
  for (int i = b; i < e; ++i) { offs[i] = excl; cursor[i] = excl; excl += deg[i]; }
  if (t == 1023) offs[NN] = part[1023];
}

__global__ void fill_kernel(const int* __restrict__ src, const int* __restrict__ dst,
                            const int* __restrict__ et, const float* __restrict__ ew,
                            const unsigned* __restrict__ mm, int* cursor,
                            int2* __restrict__ ed) {
  int e = blockIdx.x * blockDim.x + threadIdx.x;
  if (e >= NE) return;
  float mn = ord2f(~mm[0]);  // mm[0] holds ~min(ord)
  float mx = ord2f(mm[1]);
  float inv = 1.0f / (mx - mn + 1e-8f);
  int d = dst[e];
  int pos = atomicAdd(&cursor[d], 1);
  ed[pos] = make_int2(src[e] | (et[e] << 28), __float_as_int((ew[e] - mn) * inv));
}

// ---------------------------------------------------------------------------
// Aggregation (R13/R14 champion): one wave per node, unroll-4 edge gather,
// branchless relation select. Writes g[node][512] bf16 (4 relation slots);
// root/self staged by the GEMM directly from the source array.
// ---------------------------------------------------------------------------
__global__ __launch_bounds__(256) void aggregate_kernel(
    const unsigned* __restrict__ xb,   // [NN][64] packed bf16 pairs
    const int* __restrict__ offs, const int2* __restrict__ ed,
    __bf16* __restrict__ g) {
  int node = (int)((blockIdx.x * blockDim.x + threadIdx.x) >> 6);
  int lane = threadIdx.x & 63;
  if (node >= NN) return;
  int beg = offs[node], end = offs[node + 1];
  float a00 = 0.f, a01 = 0.f, a10 = 0.f, a11 = 0.f;
  float a20 = 0.f, a21 = 0.f, a30 = 0.f, a31 = 0.f;

#define LOADP(E, P0, P1)                                                \
  do {                                                                  \
    int zs_ = (E).x & 0x0FFFFFFF;                                       \
    unsigned zu_ = xb[(size_t)zs_ * 64 + lane];                         \
    P0 = __uint_as_float(zu_ << 16);                                    \
    P1 = __uint_as_float(zu_ & 0xFFFF0000u);                            \
  } while (0)
#define ACCP(E, P0, P1)                                                 \
  do {                                                                  \
    float zw_ = __int_as_float((E).y);                                  \
    unsigned zr_ = ((unsigned)(E).x) >> 28;                             \
    float zw0_ = (zr_ == 0) ? zw_ : 0.f;                                \
    float zw1_ = (zr_ == 1) ? zw_ : 0.f;                                \
    float zw2_ = (zr_ == 2) ? zw_ : 0.f;                                \
    float zw3_ = (zr_ == 3) ? zw_ : 0.f;                                \
    a00 += zw0_ * (P0); a01 += zw0_ * (P1);                             \
    a10 += zw1_ * (P0); a11 += zw1_ * (P1);                             \
    a20 += zw2_ * (P0); a21 += zw2_ * (P1);                             \
    a30 += zw3_ * (P0); a31 += zw3_ * (P1);                             \
  } while (0)

  int j = beg;
  for (; j + 4 <= end; j += 4) {
    int2 e0 = ed[j], e1 = ed[j + 1], e2 = ed[j + 2], e3 = ed[j + 3];
    float p00, p01, p10, p11, p20, p21, p30, p31;
    LOADP(e0, p00, p01); LOADP(e1, p10, p11);
    LOADP(e2, p20, p21); LOADP(e3, p30, p31);
    ACCP(e0, p00, p01); ACCP(e1, p10, p11);
    ACCP(e2, p20, p21); ACCP(e3, p30, p31);
  }
  for (; j < end; ++j) {
    int2 e = ed[j];
    float p0, p1;
    LOADP(e, p0, p1);
    ACCP(e, p0, p1);
  }
#undef LOADP
#undef ACCP

  unsigned* g32 = (unsigned*)(g + (size_t)node * GK);
  g32[0 * 64 + lane] = pkbf(a00, a01);
  g32[1 * 64 + lane] = pkbf(a10, a11);
  g32[2 * 64 + lane] = pkbf(a20, a21);
  g32[3 * 64 + lane] = pkbf(a30, a31);
}

// ---------------------------------------------------------------------------
// GEMM (R13/R14 champion): out[m][n] = [g[m][0:512] | xsrc[m][0:128]] @
// wt[n][:] + bias[n]. 512 thr (8 waves); double-buffered LDS; gld16; BK=32.
// ---------------------------------------------------------------------------
template <int OUT_BF16>
__global__ __launch_bounds__(512, 4) void gemm_kernel(
    const __bf16* __restrict__ gA, const __bf16* __restrict__ xsrc,
    const __bf16* __restrict__ wt, const float* __restrict__ bias,
    float* __restrict__ outf, __bf16* __restrict__ outb) {
  __shared__ __bf16 As[2][64 * 32];
  __shared__ __bf16 Bs[2][128 * 32];
  int tid = threadIdx.x;
  int wave = tid >> 6, lane = tid & 63;
  int wr = wave >> 1, wc = wave & 1;
  int m0 = blockIdx.x * 64;
  int rl = wr * 16 + (lane & 15);
  int kfe = (lane >> 4) * 8;  // k-slice elem offset within 32-elem row

  // ---- layout probe (self-decodes acc-slot -> (row,col); R3-verified) ----
  unsigned rowpack = 0, colpack[4];
  {
    int arow = tid >> 3, akof = (tid & 7) * 4;   // 64 rows x 32 k, bf16x4/thread
    int bn = tid >> 2, bkof = (tid & 3) * 8;     // 128 rows x 32 k, bf16x8/thread
    bf16x4 v4, one4;
    bf16x8 v8, one8;
#pragma unroll
    for (int i = 0; i < 4; ++i) one4[i] = (__bf16)1.0f;
#pragma unroll
    for (int i = 0; i < 8; ++i) one8[i] = (__bf16)1.0f;
    __bf16 rv = (__bf16)((float)arow * 0.015625f);  // row/64, exact
#pragma unroll
    for (int i = 0; i < 4; ++i) v4[i] = rv;
    *(bf16x4*)(&As[0][arow * 32 + akof]) = v4;
    *(bf16x8*)(&Bs[0][bn * 32 + bkof]) = one8;
    __syncthreads();
    bf16x8 pa = *(const bf16x8*)(&As[0][rl * 32 + kfe]);
    bf16x8 pb = *(const bf16x8*)(&Bs[0][(wc * 64 + (lane & 15)) * 32 + kfe]);
    f32x4 P1 = __builtin_amdgcn_mfma_f32_16x16x32_bf16(pa, pb, (f32x4){0.f, 0.f, 0.f, 0.f}, 0, 0, 0);
    __syncthreads();
    __bf16 cv = (__bf16)((float)bn * 0.0078125f);  // col/128, exact
#pragma unroll
    for (int i = 0; i < 8; ++i) v8[i] = cv;
    *(bf16x4*)(&As[0][arow * 32 + akof]) = one4;
    *(bf16x8*)(&Bs[0][bn * 32 + bkof]) = v8;
    __syncthreads();
    bf16x8 pa1 = *(const bf16x8*)(&As[0][rl * 32 + kfe]);
#pragma unroll
    for (int j = 0; j < 4; ++j)
      rowpack |= ((unsigned)(int)(P1[j] * 2.0f + 0.5f)) << (8 * j);
#pragma unroll
    for (int fn = 0; fn < 4; ++fn) {
      bf16x8 pbc = *(const bf16x8*)(&Bs[0][(wc * 64 + fn * 16 + (lane & 15)) * 32 + kfe]);
      f32x4 P2 = __builtin_amdgcn_mfma_f32_16x16x32_bf16(pa1, pbc, (f32x4){0.f, 0.f, 0.f, 0.f}, 0, 0, 0);
      unsigned cp = 0;
#pragma unroll
      for (int j = 0; j < 4; ++j)
        cp |= ((unsigned)(int)(P2[j] * 4.0f + 0.5f)) << (8 * j);
      colpack[fn] = cp;
    }
    __syncthreads();  // probe reads done before staging overwrites buf 0
  }

  f32x4 acc[4];
#pragma unroll
  for (int i = 0; i < 4; ++i) acc[i] = (f32x4){0.f, 0.f, 0.f, 0.f};

  // staging: tid<256 -> A tile (64x32), tid>=256 -> B tile (128x32, 2 chunks)
  // A source: k0 < 512 from g (stride GK); k0 >= 512 from xsrc (stride FD).
  auto stage = [&](int buf, int k0) {
    if (tid < 256) {
      int row = tid >> 2;
      int m = m0 + row;
      if (m >= NN) m = NN - 1;
      const __bf16* srcp = (k0 < GK)
          ? gA + (size_t)m * GK + k0 + (tid & 3) * 8
          : xsrc + (size_t)m * FD + (k0 - GK) + (tid & 3) * 8;
      gld16(srcp, &As[buf][(tid >> 6) * 512]);
    } else {
      int t = tid - 256;
      int wv = t >> 6;
      int r0 = t >> 2;
      gld16(wt + (size_t)r0 * KTOT + k0 + (t & 3) * 8, &Bs[buf][wv * 512]);
      gld16(wt + (size_t)(64 + r0) * KTOT + k0 + (t & 3) * 8, &Bs[buf][2048 + wv * 512]);
    }
  };

  stage(0, 0);
  __syncthreads();  // drains vmcnt -> buf0 ready
  int cur = 0;
  for (int step = 0; step < NSTEP; ++step) {
    if (step + 1 < NSTEP) stage(cur ^ 1, (step + 1) * 32);  // prefetch next tile
    bf16x8 a = *(const bf16x8*)(&As[cur][rl * 32 + kfe]);
#pragma unroll
    for (int fn = 0; fn < 4; ++fn) {
      bf16x8 b = *(const bf16x8*)(&Bs[cur][(wc * 64 + fn * 16 + (lane & 15)) * 32 + kfe]);
      acc[fn] = __builtin_amdgcn_mfma_f32_16x16x32_bf16(a, b, acc[fn], 0, 0, 0);
    }
    __syncthreads();  // drains prefetch + everyone's reads of buf cur
    cur ^= 1;
  }

  // epilogue: probe-decoded (row,col) per slot
#pragma unroll
  for (int fn = 0; fn < 4; ++fn) {
#pragma unroll
    for (int j = 0; j < 4; ++j) {
      int rloc = (int)((rowpack >> (8 * j)) & 255u);
      int col = (int)((colpack[fn] >> (8 * j)) & 255u);
      int m = m0 + rloc;
      if (m < NN) {
        float v = acc[fn][j] + bias[col];
        if (OUT_BF16) {
          v = fmaxf(v, 0.f);
          outb[(size_t)m * FD + col] = (__bf16)v;
        } else {
          outf[(size_t)m * FD + col] = v;
        }
      }
    }
  }
}

extern "C" void kernel_launch(void* const* d_in, const int* in_sizes, int n_in,
                              void* d_out, int out_size, void* d_ws, size_t ws_size,
                              hipStream_t stream) {
  const float* x  = (const float*)d_in[0];
  const int*   ei = (const int*)d_in[1];
  const int*   et = (const int*)d_in[2];
  const float* ew = (const float*)d_in[3];
  const float* W1 = (const float*)d_in[4];
  const float* r1 = (const float*)d_in[5];
  const float* b1 = (const float*)d_in[6];
  const float* W2 = (const float*)d_in[7];
  const float* r2 = (const float*)d_in[8];
  const float* b2 = (const float*)d_in[9];
  float* out = (float*)d_out;
  const int* src = ei;
  const int* dst = ei + NE;

  char* w = (char*)d_ws;
  // mm (8 B) and deg (NN*4) contiguous at base -> single zero-memset seeds
  // mm[0] (complement-min: 0 is identity for max), mm[1] (max seed), deg.
  unsigned* mm = (unsigned*)w;
  int* deg     = (int*)(w + 8);
  size_t o = (8 + (size_t)NN * 4 + 255) & ~(size_t)255;
  auto take = [&](size_t bytes) -> char* {
    char* p = w + o;
    o += (bytes + 255) & ~(size_t)255;
    return p;
  };
  int* offs     = (int*)take((size_t)(NN + 1) * 4);
  int* cursor   = (int*)take((size_t)NN * 4);
  int2* ed      = (int2*)take((size_t)(NE + 8) * 8);
  unsigned* xb  = (unsigned*)take((size_t)NN * 64 * 4);
  __bf16* g     = (__bf16*)take((size_t)NN * GK * 2);
  __bf16* h1    = (__bf16*)take((size_t)NN * FD * 2);
  __bf16* wt1   = (__bf16*)take((size_t)FD * KTOT * 2);
  __bf16* wt2   = (__bf16*)take((size_t)FD * KTOT * 2);
  (void)ws_size; (void)n_in; (void)in_sizes; (void)out_size;

  hipMemsetAsync(w, 0, 8 + (size_t)NN * 4, stream);
  hipLaunchKernelGGL(prep_hist_kernel, dim3((NN * FD / 4 + 255) / 256), dim3(256), 0, stream,
                     mm, deg, x, xb, W1, r1, W2, r2, wt1, wt2, dst, ew);
  hipLaunchKernelGGL(scan_kernel, dim3(1), dim3(1024), 0, stream, deg, offs, cursor);
  hipLaunchKernelGGL(fill_kernel, dim3((NE + 255) / 256), dim3(256), 0, stream,
                     src, dst, et, ew, mm, cursor, ed);
  // layer 1
  hipLaunchKernelGGL(aggregate_kernel, dim3(NN / 4), dim3(256), 0, stream, xb, offs, ed, g);
  hipLaunchKernelGGL((gemm_kernel<1>), dim3((NN + 63) / 64), dim3(512), 0, stream,
                     g, (const __bf16*)xb, wt1, b1, (float*)nullptr, h1);
  // layer 2
  hipLaunchKernelGGL(aggregate_kernel, dim3(NN / 4), dim3(256), 0, stream,
                     (const unsigned*)h1, offs, ed, g);
  hipLaunchKernelGGL((gemm_kernel<0>), dim3((NN + 63) / 64), dim3(512), 0, stream,
                     g, h1, wt2, b2, out, (__bf16*)nullptr);
}

// Round 16
// 159.190 us; speedup vs baseline: 1.2868x; 1.2868x over previous
//
#include <hip/hip_runtime.h>

#define NN 20000
#define NE 320000
#define FD 128
#define KTOT 640   // logical K: 4*128 (relations) + 128 (root/self)
#define GK 512     // columns stored in g (root staged from source directly)
#define NSTEP 20   // KTOT / 32

typedef float f32x4 __attribute__((ext_vector_type(4)));
typedef __bf16 bf16x4 __attribute__((ext_vector_type(4)));
typedef __bf16 bf16x8 __attribute__((ext_vector_type(8)));

__device__ __forceinline__ unsigned f2ord(float f) {
  unsigned u = __float_as_uint(f);
  return (u & 0x80000000u) ? ~u : (u | 0x80000000u);
}
__device__ __forceinline__ float ord2f(unsigned u) {
  return (u & 0x80000000u) ? __uint_as_float(u & 0x7FFFFFFFu) : __uint_as_float(~u);
}
__device__ __forceinline__ unsigned pkbf(float a, float b) {
  union { __bf16 h[2]; unsigned u; } p;
  p.h[0] = (__bf16)a; p.h[1] = (__bf16)b; return p.u;
}
// async global->LDS, 16B per lane; LDS dest is wave-uniform base (lane*16 implied)
__device__ __forceinline__ void gld16(const void* src, void* lds) {
  __builtin_amdgcn_global_load_lds(
      (const unsigned int __attribute__((address_space(1)))*)src,
      (unsigned int __attribute__((address_space(3)))*)lds, 16, 0, 0);
}

// prep: mm seed, deg zero, x->bf16 pack, both layers' wt (B^T) build
__global__ void prep_kernel(unsigned* mm, int* deg,
                            const float* __restrict__ x, unsigned* __restrict__ xb,
                            const float* __restrict__ W1, const float* __restrict__ r1,
                            const float* __restrict__ W2, const float* __restrict__ r2,
                            __bf16* __restrict__ wt1, __bf16* __restrict__ wt2) {
  int i = blockIdx.x * blockDim.x + threadIdx.x;
  if (i == 0) { mm[0] = 0xFFFFFFFFu; mm[1] = 0u; }
  if (i < NN) deg[i] = 0;
  if (i < 2 * FD * KTOT) {
    int which = i / (FD * KTOT);
    int rem = i % (FD * KTOT);
    int n = rem / KTOT, k = rem % KTOT;
    const float* W = which ? W2 : W1;
    const float* rt = which ? r2 : r1;
    float v = (k < 512) ? W[(size_t)k * FD + n] : rt[(size_t)(k - 512) * FD + n];
    (which ? wt2 : wt1)[rem] = (__bf16)v;
  }
  if (i < NN * FD / 4) {
    float4 v = *(const float4*)(x + (size_t)i * 4);
    uint2 p;
    p.x = pkbf(v.x, v.y);
    p.y = pkbf(v.z, v.w);
    *(uint2*)(xb + (size_t)i * 2) = p;
  }
}

__global__ void histmm_kernel(const int* __restrict__ dst, const float* __restrict__ ew,
                              int* deg, unsigned* mm) {
  __shared__ unsigned smn[256], smx[256];
  unsigned lmn = 0xFFFFFFFFu, lmx = 0u;
  for (int i = blockIdx.x * blockDim.x + threadIdx.x; i < NE; i += gridDim.x * blockDim.x) {
    atomicAdd(&deg[dst[i]], 1);
    unsigned o = f2ord(ew[i]);
    lmn = (o < lmn) ? o : lmn;
    lmx = (o > lmx) ? o : lmx;
  }
  smn[threadIdx.x] = lmn; smx[threadIdx.x] = lmx;
  __syncthreads();
  for (int s = 128; s > 0; s >>= 1) {
    if (threadIdx.x < s) {
      unsigned a = smn[threadIdx.x], b = smn[threadIdx.x + s];
      smn[threadIdx.x] = (b < a) ? b : a;
      unsigned c = smx[threadIdx.x], d = smx[threadIdx.x + s];
      smx[threadIdx.x] = (d > c) ? d : c;
    }
    __syncthreads();
  }
  if (threadIdx.x == 0) { atomicMin(&mm[0], smn[0]); atomicMax(&mm[1], smx[0]); }
}

__global__ void scan_kernel(const int* __restrict__ deg, int* offs, int* cursor) {
  __shared__ int part[1024];
  const int CH = (NN + 1023) / 1024;  // 20
  int t = threadIdx.x;
  int b = t * CH;
  int e = (b + CH < NN) ? (b + CH) : NN;
  int s = 0;
  for (int i = b; i < e; ++i) s += deg[i];
  part[t] = s;
  __syncthreads();
  for (int off = 1; off < 1024; off <<= 1) {
    int v = part[t];
    int add = (t >= off) ? part[t - off] : 0;
    __syncthreads();
    part[t] = v + add;
    __syncthreads();
  }
  int excl = (t == 0) ? 0 : part[t - 1];
  for (int i = b; i < e; ++i) { offs[i] = excl; cursor[i] = excl; excl += deg[i]; }
  if (t == 1023) offs[NN] = part[1023];
}

__global__ void fill_kernel(const int* __restrict__ src, const int* __restrict__ dst,
                            const int* __restrict__ et, const float* __restrict__ ew,
                            const unsigned* __restrict__ mm, int* cursor,
                            int2* __restrict__ ed) {
  int e = blockIdx.x * blockDim.x + threadIdx.x;
  if (e >= NE) return;
  float mn = ord2f(mm[0]), mx = ord2f(mm[1]);
  float inv = 1.0f / (mx - mn + 1e-8f);
  int d = dst[e];
  int pos = atomicAdd(&cursor[d], 1);
  ed[pos] = make_int2(src[e] | (et[e] << 28), __float_as_int((ew[e] - mn) * inv));
}

// ---------------------------------------------------------------------------
// Aggregation (R13/R14 champion): one wave per node, unroll-4 edge gather,
// branchless relation select. Writes g[node][512] bf16 (4 relation slots);
// root/self staged by the GEMM directly from the source array.
// ---------------------------------------------------------------------------
__global__ __launch_bounds__(256) void aggregate_kernel(
    const unsigned* __restrict__ xb,   // [NN][64] packed bf16 pairs
    const int* __restrict__ offs, const int2* __restrict__ ed,
    __bf16* __restrict__ g) {
  int node = (int)((blockIdx.x * blockDim.x + threadIdx.x) >> 6);
  int lane = threadIdx.x & 63;
  if (node >= NN) return;
  int beg = offs[node], end = offs[node + 1];
  float a00 = 0.f, a01 = 0.f, a10 = 0.f, a11 = 0.f;
  float a20 = 0.f, a21 = 0.f, a30 = 0.f, a31 = 0.f;

#define LOADP(E, P0, P1)                                                \
  do {                                                                  \
    int zs_ = (E).x & 0x0FFFFFFF;                                       \
    unsigned zu_ = xb[(size_t)zs_ * 64 + lane];                         \
    P0 = __uint_as_float(zu_ << 16);                                    \
    P1 = __uint_as_float(zu_ & 0xFFFF0000u);                            \
  } while (0)
#define ACCP(E, P0, P1)                                                 \
  do {                                                                  \
    float zw_ = __int_as_float((E).y);                                  \
    unsigned zr_ = ((unsigned)(E).x) >> 28;                             \
    float zw0_ = (zr_ == 0) ? zw_ : 0.f;                                \
    float zw1_ = (zr_ == 1) ? zw_ : 0.f;                                \
    float zw2_ = (zr_ == 2) ? zw_ : 0.f;                                \
    float zw3_ = (zr_ == 3) ? zw_ : 0.f;                                \
    a00 += zw0_ * (P0); a01 += zw0_ * (P1);                             \
    a10 += zw1_ * (P0); a11 += zw1_ * (P1);                             \
    a20 += zw2_ * (P0); a21 += zw2_ * (P1);                             \
    a30 += zw3_ * (P0); a31 += zw3_ * (P1);                             \
  } while (0)

  int j = beg;
  for (; j + 4 <= end; j += 4) {
    int2 e0 = ed[j], e1 = ed[j + 1], e2 = ed[j + 2], e3 = ed[j + 3];
    float p00, p01, p10, p11, p20, p21, p30, p31;
    LOADP(e0, p00, p01); LOADP(e1, p10, p11);
    LOADP(e2, p20, p21); LOADP(e3, p30, p31);
    ACCP(e0, p00, p01); ACCP(e1, p10, p11);
    ACCP(e2, p20, p21); ACCP(e3, p30, p31);
  }
  for (; j < end; ++j) {
    int2 e = ed[j];
    float p0, p1;
    LOADP(e, p0, p1);
    ACCP(e, p0, p1);
  }
#undef LOADP
#undef ACCP

  unsigned* g32 = (unsigned*)(g + (size_t)node * GK);
  g32[0 * 64 + lane] = pkbf(a00, a01);
  g32[1 * 64 + lane] = pkbf(a10, a11);
  g32[2 * 64 + lane] = pkbf(a20, a21);
  g32[3 * 64 + lane] = pkbf(a30, a31);
}

// ---------------------------------------------------------------------------
// GEMM (R13/R14 champion): out[m][n] = [g[m][0:512] | xsrc[m][0:128]] @
// wt[n][:] + bias[n]. 512 thr (8 waves); double-buffered LDS; gld16; BK=32.
// ---------------------------------------------------------------------------
template <int OUT_BF16>
__global__ __launch_bounds__(512, 4) void gemm_kernel(
    const __bf16* __restrict__ gA, const __bf16* __restrict__ xsrc,
    const __bf16* __restrict__ wt, const float* __restrict__ bias,
    float* __restrict__ outf, __bf16* __restrict__ outb) {
  __shared__ __bf16 As[2][64 * 32];
  __shared__ __bf16 Bs[2][128 * 32];
  int tid = threadIdx.x;
  int wave = tid >> 6, lane = tid & 63;
  int wr = wave >> 1, wc = wave & 1;
  int m0 = blockIdx.x * 64;
  int rl = wr * 16 + (lane & 15);
  int kfe = (lane >> 4) * 8;  // k-slice elem offset within 32-elem row

  // ---- layout probe (self-decodes acc-slot -> (row,col); R3-verified) ----
  unsigned rowpack = 0, colpack[4];
  {
    int arow = tid >> 3, akof = (tid & 7) * 4;   // 64 rows x 32 k, bf16x4/thread
    int bn = tid >> 2, bkof = (tid & 3) * 8;     // 128 rows x 32 k, bf16x8/thread
    bf16x4 v4, one4;
    bf16x8 v8, one8;
#pragma unroll
    for (int i = 0; i < 4; ++i) one4[i] = (__bf16)1.0f;
#pragma unroll
    for (int i = 0; i < 8; ++i) one8[i] = (__bf16)1.0f;
    __bf16 rv = (__bf16)((float)arow * 0.015625f);  // row/64, exact
#pragma unroll
    for (int i = 0; i < 4; ++i) v4[i] = rv;
    *(bf16x4*)(&As[0][arow * 32 + akof]) = v4;
    *(bf16x8*)(&Bs[0][bn * 32 + bkof]) = one8;
    __syncthreads();
    bf16x8 pa = *(const bf16x8*)(&As[0][rl * 32 + kfe]);
    bf16x8 pb = *(const bf16x8*)(&Bs[0][(wc * 64 + (lane & 15)) * 32 + kfe]);
    f32x4 P1 = __builtin_amdgcn_mfma_f32_16x16x32_bf16(pa, pb, (f32x4){0.f, 0.f, 0.f, 0.f}, 0, 0, 0);
    __syncthreads();
    __bf16 cv = (__bf16)((float)bn * 0.0078125f);  // col/128, exact
#pragma unroll
    for (int i = 0; i < 8; ++i) v8[i] = cv;
    *(bf16x4*)(&As[0][arow * 32 + akof]) = one4;
    *(bf16x8*)(&Bs[0][bn * 32 + bkof]) = v8;
    __syncthreads();
    bf16x8 pa1 = *(const bf16x8*)(&As[0][rl * 32 + kfe]);
#pragma unroll
    for (int j = 0; j < 4; ++j)
      rowpack |= ((unsigned)(int)(P1[j] * 2.0f + 0.5f)) << (8 * j);
#pragma unroll
    for (int fn = 0; fn < 4; ++fn) {
      bf16x8 pbc = *(const bf16x8*)(&Bs[0][(wc * 64 + fn * 16 + (lane & 15)) * 32 + kfe]);
      f32x4 P2 = __builtin_amdgcn_mfma_f32_16x16x32_bf16(pa1, pbc, (f32x4){0.f, 0.f, 0.f, 0.f}, 0, 0, 0);
      unsigned cp = 0;
#pragma unroll
      for (int j = 0; j < 4; ++j)
        cp |= ((unsigned)(int)(P2[j] * 4.0f + 0.5f)) << (8 * j);
      colpack[fn] = cp;
    }
    __syncthreads();  // probe reads done before staging overwrites buf 0
  }

  f32x4 acc[4];
#pragma unroll
  for (int i = 0; i < 4; ++i) acc[i] = (f32x4){0.f, 0.f, 0.f, 0.f};

  // staging: tid<256 -> A tile (64x32), tid>=256 -> B tile (128x32, 2 chunks)
  // A source: k0 < 512 from g (stride GK); k0 >= 512 from xsrc (stride FD).
  auto stage = [&](int buf, int k0) {
    if (tid < 256) {
      int row = tid >> 2;
      int m = m0 + row;
      if (m >= NN) m = NN - 1;
      const __bf16* srcp = (k0 < GK)
          ? gA + (size_t)m * GK + k0 + (tid & 3) * 8
          : xsrc + (size_t)m * FD + (k0 - GK) + (tid & 3) * 8;
      gld16(srcp, &As[buf][(tid >> 6) * 512]);
    } else {
      int t = tid - 256;
      int wv = t >> 6;
      int r0 = t >> 2;
      gld16(wt + (size_t)r0 * KTOT + k0 + (t & 3) * 8, &Bs[buf][wv * 512]);
      gld16(wt + (size_t)(64 + r0) * KTOT + k0 + (t & 3) * 8, &Bs[buf][2048 + wv * 512]);
    }
  };

  stage(0, 0);
  __syncthreads();  // drains vmcnt -> buf0 ready
  int cur = 0;
  for (int step = 0; step < NSTEP; ++step) {
    if (step + 1 < NSTEP) stage(cur ^ 1, (step + 1) * 32);  // prefetch next tile
    bf16x8 a = *(const bf16x8*)(&As[cur][rl * 32 + kfe]);
#pragma unroll
    for (int fn = 0; fn < 4; ++fn) {
      bf16x8 b = *(const bf16x8*)(&Bs[cur][(wc * 64 + fn * 16 + (lane & 15)) * 32 + kfe]);
      acc[fn] = __builtin_amdgcn_mfma_f32_16x16x32_bf16(a, b, acc[fn], 0, 0, 0);
    }
    __syncthreads();  // drains prefetch + everyone's reads of buf cur
    cur ^= 1;
  }

  // epilogue: probe-decoded (row,col) per slot
#pragma unroll
  for (int fn = 0; fn < 4; ++fn) {
#pragma unroll
    for (int j = 0; j < 4; ++j) {
      int rloc = (int)((rowpack >> (8 * j)) & 255u);
      int col = (int)((colpack[fn] >> (8 * j)) & 255u);
      int m = m0 + rloc;
      if (m < NN) {
        float v = acc[fn][j] + bias[col];
        if (OUT_BF16) {
          v = fmaxf(v, 0.f);
          outb[(size_t)m * FD + col] = (__bf16)v;
        } else {
          outf[(size_t)m * FD + col] = v;
        }
      }
    }
  }
}

extern "C" void kernel_launch(void* const* d_in, const int* in_sizes, int n_in,
                              void* d_out, int out_size, void* d_ws, size_t ws_size,
                              hipStream_t stream) {
  const float* x  = (const float*)d_in[0];
  const int*   ei = (const int*)d_in[1];
  const int*   et = (const int*)d_in[2];
  const float* ew = (const float*)d_in[3];
  const float* W1 = (const float*)d_in[4];
  const float* r1 = (const float*)d_in[5];
  const float* b1 = (const float*)d_in[6];
  const float* W2 = (const float*)d_in[7];
  const float* r2 = (const float*)d_in[8];
  const float* b2 = (const float*)d_in[9];
  float* out = (float*)d_out;
  const int* src = ei;
  const int* dst = ei + NE;

  char* w = (char*)d_ws;
  size_t o = 0;
  auto take = [&](size_t bytes) -> char* {
    char* p = w + o;
    o += (bytes + 255) & ~(size_t)255;
    return p;
  };
  unsigned* mm  = (unsigned*)take(8);
  int* deg      = (int*)take((size_t)NN * 4);
  int* offs     = (int*)take((size_t)(NN + 1) * 4);
  int* cursor   = (int*)take((size_t)NN * 4);
  int2* ed      = (int2*)take((size_t)(NE + 8) * 8);
  unsigned* xb  = (unsigned*)take((size_t)NN * 64 * 4);
  __bf16* g     = (__bf16*)take((size_t)NN * GK * 2);
  __bf16* h1    = (__bf16*)take((size_t)NN * FD * 2);
  __bf16* wt1   = (__bf16*)take((size_t)FD * KTOT * 2);
  __bf16* wt2   = (__bf16*)take((size_t)FD * KTOT * 2);
  (void)ws_size; (void)n_in; (void)in_sizes; (void)out_size;

  hipLaunchKernelGGL(prep_kernel, dim3((NN * FD / 4 + 255) / 256), dim3(256), 0, stream,
                     mm, deg, x, xb, W1, r1, W2, r2, wt1, wt2);
  hipLaunchKernelGGL(histmm_kernel, dim3(512), dim3(256), 0, stream, dst, ew, deg, mm);
  hipLaunchKernelGGL(scan_kernel, dim3(1), dim3(1024), 0, stream, deg, offs, cursor);
  hipLaunchKernelGGL(fill_kernel, dim3((NE + 255) / 256), dim3(256), 0, stream,
                     src, dst, et, ew, mm, cursor, ed);
  // layer 1
  hipLaunchKernelGGL(aggregate_kernel, dim3(NN / 4), dim3(256), 0, stream, xb, offs, ed, g);
  hipLaunchKernelGGL((gemm_kernel<1>), dim3((NN + 63) / 64), dim3(512), 0, stream,
                     g, (const __bf16*)xb, wt1, b1, (float*)nullptr, h1);
  // layer 2
  hipLaunchKernelGGL(aggregate_kernel, dim3(NN / 4), dim3(256), 0, stream,
                     (const unsigned*)h1, offs, ed, g);
  hipLaunchKernelGGL((gemm_kernel<0>), dim3((NN + 63) / 64), dim3(512), 0, stream,
                     g, h1, wt2, b2, out, (__bf16*)nullptr);
}